// Round 2
// baseline (635.948 us; speedup 1.0000x reference)
//
#include <hip/hip_runtime.h>

// Potts energy:  U (scalar) and U_i (N,C);  B=1, N=8192, K=32, C=21.
//
// v3: barrier-free per-wave streaming pipeline.
// v2 streamed the whole 56.4 KB J-row per block but paid a full vmcnt(0)
// drain at __syncthreads() plus block-launch gaps with only 2 blocks/CU.
// v3 gives each WAVE one node (4 nodes per 256-thread block, no cross-wave
// sharing, zero __syncthreads): the row is consumed in 8 groups of 4
// k-blocks (7056 B), double-buffered in two 7168-B LDS slots per wave,
// advanced with counted s_waitcnt vmcnt(7) so 7-14 KB of loads stay in
// flight per wave at all times (112 KB/CU >> latency-BW product ~10 KB).
// Neighbor states/masks are pre-broadcast to registers via __shfl before
// any async issue, so no compiler vmcnt waits land inside the loop.
// Gather accumulates in 2 registers per lane (fixed c per lane), one LDS
// atomic per lane at the end, then a per-wave epilogue.

#define KK 32
#define CC 21
#define ROWF (KK * CC * CC)          // 14112 floats per node
#define ROWB (ROWF * 4)              // 56448 B per node
#define GRPK 4                       // k-blocks per group
#define NGRP (KK / GRPK)             // 8 groups
#define GRPB (GRPK * CC * CC * 4)    // 7056 B per group
#define GISS 7                       // 1-KiB async issues per group
#define SLOTF (GISS * 256)           // 1792 floats = 7168 B per LDS slot
#define WPB 4                        // waves (nodes) per block

typedef __attribute__((address_space(3))) void       lds_void_t;
typedef __attribute__((address_space(1))) const void gbl_void_t;

__global__ __launch_bounds__(256) void potts_kernel(
    const int* __restrict__ S,
    const float* __restrict__ h,
    const float* __restrict__ J,
    const int* __restrict__ edge_idx,
    const float* __restrict__ mask_i,
    const float* __restrict__ mask_ij,
    float* __restrict__ out,            // out[0]=U, out[1..]=U_i (N*C)
    int N)
{
    const int tid  = threadIdx.x;
    const int wave = tid >> 6;
    const int lane = tid & 63;
    const int i    = blockIdx.x * WPB + wave;

    __shared__ float jrow[WPB][2][SLOTF];   // 57344 B
    __shared__ float accs[WPB][CC];         //   336 B

    if (i >= N) return;                     // wave-uniform; no barriers used

    if (lane < CC) accs[wave][lane] = 0.0f;

    // ---- neighbor metadata (completes while async queue is still empty) ----
    int   sjv = 0; float mv = 0.0f;
    if (lane < KK) {
        int e = edge_idx[i * KK + lane];
        sjv = S[e];
        mv  = mask_ij[i * KK + lane];
    }

    // Per-lane element assignment: element A = idx lane (kk 0..3), element B
    // (lanes 0..19) = idx 64+lane -> kk=3, c=lane+1.  Covers all 4*21 (kk,c).
    const int kk_a   = lane / 21;                 // 63/21 = 3
    const int c_a    = lane - kk_a * 21;
    const int c_b    = lane + 1;
    const int base_a = kk_a * (CC * CC) + c_a * CC;
    const int base_b = 3 * (CC * CC) + c_b * CC;

    int   s_a[NGRP], s_b[NGRP];
    float m_a[NGRP], m_b[NGRP];
#pragma unroll
    for (int g = 0; g < NGRP; ++g) {              // consumes sjv/mv NOW, so
        s_a[g] = __shfl(sjv, g * GRPK + kk_a);    // no vmcnt waits needed in
        m_a[g] = __shfl(mv,  g * GRPK + kk_a);    // the streaming loop
        s_b[g] = __shfl(sjv, g * GRPK + 3);
        m_b[g] = __shfl(mv,  g * GRPK + 3);
    }

    const char*  Jb     = (const char*)J + (size_t)i * ROWB;
    const size_t maxoff = (size_t)(N - i) * ROWB - 16;  // clamp, rel. to Jb

    // Stage group g into per-wave LDS slot: uniform dest (HW adds lane*16),
    // per-lane global source.  Only the final group can overrun the row
    // (112 B into the next row; clamped at the end of J).
#define ISSUE(g, slot)                                                        \
    {                                                                         \
        char* lb = (char*)&jrow[wave][slot][0];                               \
        _Pragma("unroll")                                                     \
        for (int j = 0; j < GISS; ++j) {                                      \
            size_t go = (size_t)(g) * GRPB + (size_t)(j << 10) + (lane << 4); \
            if ((g) == NGRP - 1 && go > maxoff) go = maxoff;                  \
            __builtin_amdgcn_global_load_lds((gbl_void_t*)(Jb + go),          \
                                             (lds_void_t*)(lb + (j << 10)),   \
                                             16, 0, 0);                       \
        }                                                                     \
    }

    ISSUE(0, 0);
    ISSUE(1, 1);

    float r0 = 0.0f, r1 = 0.0f;
#pragma unroll
    for (int g = 0; g < NGRP; ++g) {
        // group g resident once <=7 loads (the NEXT group) remain outstanding
        if (g < NGRP - 1) { asm volatile("s_waitcnt vmcnt(7)" ::: "memory"); }
        else              { asm volatile("s_waitcnt vmcnt(0)" ::: "memory"); }
        __builtin_amdgcn_sched_barrier(0);

        const float* slot = &jrow[wave][g & 1][0];
        float va = slot[base_a + s_a[g]];
        float vb = (lane < 20) ? slot[base_b + s_b[g]] : 0.0f;

        // LDS reads must land in regs before this slot is re-staged
        asm volatile("s_waitcnt lgkmcnt(0)" ::: "memory");
        __builtin_amdgcn_sched_barrier(0);

        if (g < NGRP - 2) ISSUE(g + 2, g & 1);

        r0 += va * m_a[g];
        r1 += vb * m_b[g];
    }
#undef ISSUE

    // ---- per-wave combine + epilogue (wave-synchronous, no barriers) ----
    atomicAdd(&accs[wave][c_a], r0);
    if (lane < 20) atomicAdd(&accs[wave][c_b], r1);
    asm volatile("s_waitcnt lgkmcnt(0)" ::: "memory");
    __builtin_amdgcn_sched_barrier(0);

    const int   cl = (lane < CC) ? lane : 0;
    const float mi = mask_i[i];
    const float av = accs[wave][cl];
    const float ui = h[i * CC + cl] * mi + av;
    if (lane < CC) out[1 + i * CC + lane] = ui;

    const int   si     = S[i];
    const float ui_sel = __shfl(ui, si);
    const float av_sel = __shfl(av, si);
    if (lane == 0) atomicAdd(out, ui_sel - 0.5f * av_sel);  // device-scope
}

extern "C" void kernel_launch(void* const* d_in, const int* in_sizes, int n_in,
                              void* d_out, int out_size, void* d_ws, size_t ws_size,
                              hipStream_t stream) {
    const int*   S        = (const int*)d_in[0];
    const float* h        = (const float*)d_in[1];
    const float* J        = (const float*)d_in[2];
    const int*   edge_idx = (const int*)d_in[3];
    const float* mask_i   = (const float*)d_in[4];
    const float* mask_ij  = (const float*)d_in[5];
    float* out = (float*)d_out;

    const int N = in_sizes[0];   // 8192 nodes

    // Harness poisons d_out with 0xAA; U is atomically accumulated -> zero it.
    hipMemsetAsync(out, 0, sizeof(float), stream);

    const int grid = (N + WPB - 1) / WPB;
    potts_kernel<<<grid, 256, 0, stream>>>(S, h, J, edge_idx, mask_i, mask_ij,
                                           out, N);
}

// Round 3
// 615.751 us; speedup vs baseline: 1.0328x; 1.0328x over previous
//
#include <hip/hip_runtime.h>

// Potts energy:  U (scalar) and U_i (N,C);  B=1, N=8192, K=32, C=21.
//
// v4 = v2 (best-measured, 617.3 us) + metadata-load hoist.
//
// Session model (3 rounds of evidence): the timed window is dominated by
// ~2 harness fillBufferAligned resets (1.85 GB @ ~80% HBM peak, ~285 us
// each) that kernel code cannot touch; the potts kernel itself never
// appears in the rocprof top-5 (< 283 us) and is at/near its 462 MB
// J-stream floor (~73 us @ 6.3 TB/s). v3's barrier-free wave pipeline
// measured worse (635.9) than v2's simple block-stream (617.3), so we
// revert to v2's structure:
//
//   One 256-thread block per node: stream the whole 56.4 KB J-row into
//   LDS with 56 x 1 KiB async global_load_lds issues (width=16, fully
//   coalesced, no VGPR round-trip), then gather the 672 needed elements
//   from LDS (stride-21-dword = odd = conflict-light) and LDS-atomicAdd
//   into acc[c]. Epilogue: U_i = h*mask_i + acc; U via one global atomic.
//
// v4 change: edge_idx/S/mask_ij loads are issued BEFORE the async J
// stream, so their in-order vmcnt completion does not require draining
// the 56-deep async queue before the s_j/m_ij LDS writes can retire.

#define KK 32
#define CC 21
#define ROWF (KK * CC * CC)          // 14112 floats per node
#define ROWB (ROWF * 4)              // 56448 bytes per node
#define NCHUNK 56                    // ceil(56448/1024): 1 KiB async chunks
#define ROWF_PAD (NCHUNK * 256)      // 14336 floats (57344 B) -- tail pad
#define PAIRS (KK * CC)              // 672 gathered elements per node

typedef __attribute__((address_space(3))) void       lds_void_t;
typedef __attribute__((address_space(1))) const void gbl_void_t;

__global__ __launch_bounds__(256) void potts_kernel(
    const int* __restrict__ S,
    const float* __restrict__ h,
    const float* __restrict__ J,
    const int* __restrict__ edge_idx,
    const float* __restrict__ mask_i,
    const float* __restrict__ mask_ij,
    float* __restrict__ out)            // out[0]=U, out[1..]=U_i (N*C)
{
    const int i    = blockIdx.x;
    const int tid  = threadIdx.x;
    const int lane = tid & 63;

    __shared__ float jrow[ROWF_PAD];
    __shared__ int   s_j[KK];
    __shared__ float m_ij[KK];
    __shared__ float acc[CC];
    __shared__ float ui_s[CC];

    // ---- metadata first: completes while the async J-stream is in flight
    int   e = 0; float mv = 0.0f;
    if (tid < KK) {
        e  = edge_idx[i * KK + tid];
        mv = mask_ij[i * KK + tid];
    }
    if (tid < CC) acc[tid] = 0.0f;

    const char* Jb = (const char*)(J + (size_t)i * ROWF);

    // ---- async coalesced stage: 56 x 1 KiB chunks, 4 waves x 14 issues ----
    // HW writes LDS at (uniform base + lane*16); global src is per-lane.
    const int wave = tid >> 6;
#pragma unroll
    for (int j = 0; j < 14; ++j) {
        int q       = (j << 2) + wave;       // chunk 0..55
        int lds_off = q << 10;               // byte offset into jrow
        int g_off   = lds_off + (lane << 4);
        if (g_off > ROWB - 16) g_off = ROWB - 16;  // tail: dup reads, pad writes
        __builtin_amdgcn_global_load_lds(
            (gbl_void_t*)(Jb + g_off),
            (lds_void_t*)((char*)jrow + lds_off),
            16, 0, 0);
    }

    if (tid < KK) {
        s_j[tid]  = S[e];
        m_ij[tid] = mv;
    }
    __syncthreads();   // drains vmcnt(0)+lgkmcnt(0) before s_barrier

    // ---- gather phase from LDS (stride 21 dwords = odd = conflict-light)
    float vals[3];
    int   cs[3];
#pragma unroll
    for (int j = 0; j < 3; ++j) {
        int idx = tid + j * 256;
        if (idx < PAIRS) {
            int k = idx / CC;                // magic-mul, compile-time const
            int c = idx - k * CC;
            cs[j]   = c;
            vals[j] = jrow[k * (CC * CC) + c * CC + s_j[k]] * m_ij[k];
        } else {
            cs[j]   = -1;
            vals[j] = 0.0f;
        }
    }
#pragma unroll
    for (int j = 0; j < 3; ++j) {
        if (cs[j] >= 0) atomicAdd(&acc[cs[j]], vals[j]);
    }
    __syncthreads();

    if (tid < CC) {
        float ui = h[i * CC + tid] * mask_i[i] + acc[tid];
        out[1 + i * CC + tid] = ui;
        ui_s[tid] = ui;
    }
    __syncthreads();

    if (tid == 0) {
        int s = S[i];
        float u = ui_s[s] - 0.5f * acc[s];
        atomicAdd(out, u);   // device-scope by default on CDNA
    }
}

extern "C" void kernel_launch(void* const* d_in, const int* in_sizes, int n_in,
                              void* d_out, int out_size, void* d_ws, size_t ws_size,
                              hipStream_t stream) {
    const int*   S        = (const int*)d_in[0];
    const float* h        = (const float*)d_in[1];
    const float* J        = (const float*)d_in[2];
    const int*   edge_idx = (const int*)d_in[3];
    const float* mask_i   = (const float*)d_in[4];
    const float* mask_ij  = (const float*)d_in[5];
    float* out = (float*)d_out;

    const int N = in_sizes[0];   // 8192 nodes

    // Harness poisons d_out with 0xAA; U is atomically accumulated -> zero it.
    hipMemsetAsync(out, 0, sizeof(float), stream);

    potts_kernel<<<N, 256, 0, stream>>>(S, h, J, edge_idx, mask_i, mask_ij, out);
}